// Round 8
// baseline (420.769 us; speedup 1.0000x reference)
//
#include <hip/hip_runtime.h>
#include <hip/hip_fp16.h>
#include <math.h>

#define N_NODES 100000
#define N_EDGES 1600000
#define F_DIM 128
#define C_DIM 40
#define ZROW N_NODES                      // index of the all-zero xws row (gather clamp target)
#define ZOFFW ((uint)(ZROW * C_DIM * 4 / 2))   // byte offset of zero row in xws_h (80-B rows)

#define NBUCK 782            // ceil(100000 / 128) row-buckets of 128 rows
#define EB 4096              // edges per histogram block
#define NBLK_BUCKET ((N_EDGES + EB - 1) / EB)   // 391

typedef unsigned long long ull;
typedef unsigned int uint;
typedef unsigned short ushort;

typedef __attribute__((ext_vector_type(8))) short bf16x8;
typedef __attribute__((ext_vector_type(4))) float f32x4;

__device__ __forceinline__ ushort f2bf(float f) {   // fp32 -> bf16 bits, RNE
    uint u = __float_as_uint(f);
    uint r = u + 0x7FFFu + ((u >> 16) & 1u);
    return (ushort)(r >> 16);
}

// fp16-pair accumulate: ax += h.x, ay += h.y (fp32 accumulation)
#if __has_builtin(__builtin_amdgcn_fdot2)
typedef __attribute__((ext_vector_type(2))) _Float16 h2f;
__device__ __forceinline__ void acc_xy(uint u, float& ax, float& ay) {
    union { uint u; h2f h; } z; z.u = u;
    union { uint u; h2f h; } ox; ox.u = 0x00003C00u;   // (1.0h, 0.0h)
    union { uint u; h2f h; } oy; oy.u = 0x3C000000u;   // (0.0h, 1.0h)
    ax = __builtin_amdgcn_fdot2(z.h, ox.h, ax, false);
    ay = __builtin_amdgcn_fdot2(z.h, oy.h, ay, false);
}
#else
__device__ __forceinline__ void acc_xy(uint u, float& ax, float& ay) {
    float2 v = __half22float2(*reinterpret_cast<__half2*>(&u));
    ax += v.x; ay += v.y;
}
#endif

__device__ __forceinline__ void cnt_xy(uint u, int& ix, int& iy) {
    ix += (u & 0xffffu) ? 1 : 0;
    iy += (u >> 16) ? 1 : 0;
}

#define RFL(v) __builtin_amdgcn_readfirstlane(v)

// ---------------- fused prep: per-row degree atomics + LDS bucket histogram + x -> fp16 encode ----------------
// Encoding: masked-out -> 0x0000 exactly; observed -> fp16(x), +0.0 forced to minimal
// subnormal so "observed" <=> bits != 0.

#define G_NODE ((N_NODES + 3) / 4)         // 25000 (wave per node)

__global__ __launch_bounds__(256) void k_prep(const int* __restrict__ row,
                                              const int* __restrict__ mask,
                                              const float* __restrict__ x,
                                              int* __restrict__ bcnt,
                                              int* __restrict__ rcnt,
                                              __half* __restrict__ xh) {
    if (blockIdx.x < NBLK_BUCKET) {
        __shared__ int lh[NBUCK];
        int t = threadIdx.x;
        int base = blockIdx.x * EB;
        int cnt = min(EB, N_EDGES - base);
        for (int i = t; i < NBUCK; i += 256) lh[i] = 0;
        __syncthreads();
        for (int i = t; i < cnt; i += 256) {
            int r = row[base + i];
            atomicAdd(&lh[r >> 7], 1);
            atomicAdd(&rcnt[r], 1);          // global per-row degree
        }
        __syncthreads();
        for (int b = t; b < NBUCK; b += 256) {
            int c = lh[b];
            if (c) atomicAdd(&bcnt[b], c);
        }
        return;
    }
    int nb = blockIdx.x - NBLK_BUCKET;
    int wv = threadIdx.x >> 6;
    int l = threadIdx.x & 63;
    int wid = nb * 4 + wv;                 // < 100000 exactly
    // lane owns feature pair (2l, 2l+1)
    int2 m2 = ((const int2*)mask)[(size_t)wid * 64 + l];
    float2 x2 = ((const float2*)x)[(size_t)wid * 64 + l];
    ushort e0 = 0, e1 = 0;
    if (m2.x) { e0 = __half_as_ushort(__float2half(x2.x)); if (e0 == 0) e0 = 1; }
    if (m2.y) { e1 = __half_as_ushort(__float2half(x2.y)); if (e1 == 0) e1 = 1; }
    ((uint*)xh)[(size_t)wid * 64 + l] = (uint)e0 | ((uint)e1 << 16);
}

// ---------------- bucket-count exclusive scan (1 block) ----------------

__global__ __launch_bounds__(256) void k_bscan(const int* __restrict__ bcnt,
                                               int* __restrict__ bbase) {
    __shared__ int partial[256];
    int t = threadIdx.x;
    int b4 = t * 4;
    int v0 = (b4 + 0 < NBUCK) ? bcnt[b4 + 0] : 0;
    int v1 = (b4 + 1 < NBUCK) ? bcnt[b4 + 1] : 0;
    int v2 = (b4 + 2 < NBUCK) ? bcnt[b4 + 2] : 0;
    int v3 = (b4 + 3 < NBUCK) ? bcnt[b4 + 3] : 0;
    int s0 = v0, s1 = s0 + v1, s2 = s1 + v2, s3 = s2 + v3;
    partial[t] = s3;
    __syncthreads();
    for (int d = 1; d < 256; d <<= 1) {
        int xv = (t >= d) ? partial[t - d] : 0;
        __syncthreads();
        partial[t] += xv;
        __syncthreads();
    }
    int excl = partial[t] - s3;
    if (b4 + 0 < NBUCK) bbase[b4 + 0] = excl;
    if (b4 + 1 < NBUCK) bbase[b4 + 1] = excl + s0;
    if (b4 + 2 < NBUCK) bbase[b4 + 2] = excl + s1;
    if (b4 + 3 < NBUCK) bbase[b4 + 3] = excl + s2;
    if (t == 255) bbase[NBUCK] = partial[255];   // == N_EDGES
}

// ---------------- per-row offsets: scan 128 row-counts within each bucket ----------------

__global__ __launch_bounds__(128) void k_rowoff(const int* __restrict__ rcnt,
                                                const int* __restrict__ bbase,
                                                int* __restrict__ off,
                                                float* __restrict__ dinv,
                                                int* __restrict__ gfill) {
    __shared__ int lex[128];
    int b = blockIdx.x;
    int t = threadIdx.x;
    int r = (b << 7) + t;
    int v = (r < N_NODES) ? rcnt[r] : 0;
    lex[t] = v;
    __syncthreads();
    for (int d = 1; d < 128; d <<= 1) {
        int xv = (t >= d) ? lex[t - d] : 0;
        __syncthreads();
        lex[t] += xv;
        __syncthreads();
    }
    if (r < N_NODES) {
        int o = bbase[b] + lex[t] - v;
        off[r] = o;
        gfill[r] = o;
        dinv[r] = rsqrtf((float)v + 1.0f);
    }
}

// ---------------- edge placement: direct atomic scatter (order within row irrelevant: sum) ----------------

__global__ __launch_bounds__(256) void k_place(const int* __restrict__ row,
                                               const int* __restrict__ col,
                                               int* __restrict__ gfill,
                                               int* __restrict__ scol) {
    int i = blockIdx.x * 256 + threadIdx.x;
    if (i < N_EDGES) {
        int r = row[i];
        int c = col[i];
        int p = atomicAdd(&gfill[r], 1);
        scol[p] = c;
    }
}

// ---------------- PaGNN masked-mean aggregation: wave/node, scalar ids, SGPR-base gather ----------------
// (round-0 structure — measured 57.2/57.0 us, at the L2-miss-path floor for 256-B rows)

__global__ __launch_bounds__(256) void k_agg(const __half* __restrict__ xh,
                                             const int* __restrict__ scol,
                                             const int* __restrict__ off, const int* __restrict__ cnt,
                                             uint* __restrict__ hb16) {
    int wv = threadIdx.x >> 6;
    int wid = blockIdx.x * 4 + wv;
    int l = threadIdx.x & 63;
    if (wid >= N_NODES) return;
    int swid = RFL(wid);
    int sstart = RFL(off[swid]);
    int slen = RFL(cnt[swid]);
    const uint* xu = (const uint*)xh;   // index: node*64 + l  (features 2l, 2l+1)

    float ax0 = 0.f, ay0 = 0.f, ax1 = 0.f, ay1 = 0.f;
    float ax2 = 0.f, ay2 = 0.f, ax3 = 0.f, ay3 = 0.f;
    int ix0 = 0, iy0 = 0, ix1 = 0, iy1 = 0;
    int ix2 = 0, iy2 = 0, ix3 = 0, iy3 = 0;

    int j = 0;
    for (; j + 8 <= slen; j += 8) {
        int c0 = RFL(scol[sstart + j + 0]);
        int c1 = RFL(scol[sstart + j + 1]);
        int c2 = RFL(scol[sstart + j + 2]);
        int c3 = RFL(scol[sstart + j + 3]);
        int c4 = RFL(scol[sstart + j + 4]);
        int c5 = RFL(scol[sstart + j + 5]);
        int c6 = RFL(scol[sstart + j + 6]);
        int c7 = RFL(scol[sstart + j + 7]);
        uint u0 = xu[(size_t)c0 * 64 + l];
        uint u1 = xu[(size_t)c1 * 64 + l];
        uint u2 = xu[(size_t)c2 * 64 + l];
        uint u3 = xu[(size_t)c3 * 64 + l];
        uint u4 = xu[(size_t)c4 * 64 + l];
        uint u5 = xu[(size_t)c5 * 64 + l];
        uint u6 = xu[(size_t)c6 * 64 + l];
        uint u7 = xu[(size_t)c7 * 64 + l];
        acc_xy(u0, ax0, ay0); cnt_xy(u0, ix0, iy0);
        acc_xy(u1, ax1, ay1); cnt_xy(u1, ix1, iy1);
        acc_xy(u2, ax2, ay2); cnt_xy(u2, ix2, iy2);
        acc_xy(u3, ax3, ay3); cnt_xy(u3, ix3, iy3);
        acc_xy(u4, ax0, ay0); cnt_xy(u4, ix0, iy0);
        acc_xy(u5, ax1, ay1); cnt_xy(u5, ix1, iy1);
        acc_xy(u6, ax2, ay2); cnt_xy(u6, ix2, iy2);
        acc_xy(u7, ax3, ay3); cnt_xy(u7, ix3, iy3);
    }
    for (; j + 4 <= slen; j += 4) {
        int c0 = RFL(scol[sstart + j + 0]);
        int c1 = RFL(scol[sstart + j + 1]);
        int c2 = RFL(scol[sstart + j + 2]);
        int c3 = RFL(scol[sstart + j + 3]);
        uint u0 = xu[(size_t)c0 * 64 + l];
        uint u1 = xu[(size_t)c1 * 64 + l];
        uint u2 = xu[(size_t)c2 * 64 + l];
        uint u3 = xu[(size_t)c3 * 64 + l];
        acc_xy(u0, ax0, ay0); cnt_xy(u0, ix0, iy0);
        acc_xy(u1, ax1, ay1); cnt_xy(u1, ix1, iy1);
        acc_xy(u2, ax2, ay2); cnt_xy(u2, ix2, iy2);
        acc_xy(u3, ax3, ay3); cnt_xy(u3, ix3, iy3);
    }
    for (; j < slen; j++) {
        int c0 = RFL(scol[sstart + j]);
        uint u0 = xu[(size_t)c0 * 64 + l];
        acc_xy(u0, ax0, ay0); cnt_xy(u0, ix0, iy0);
    }

    float ax = (ax0 + ax1) + (ax2 + ax3);
    float ay = (ay0 + ay1) + (ay2 + ay3);
    float dx = (float)((ix0 + ix1) + (ix2 + ix3));
    float dy = (float)((iy0 + iy1) + (iy2 + iy3));
    float hx = ax / fmaxf(dx, 1.0f);
    float hy = ay / fmaxf(dy, 1.0f);
    hb16[(size_t)wid * 64 + l] = (uint)f2bf(hx) | ((uint)f2bf(hy) << 16);
}

// ---------------- fused MLP (persistent MFMA): xws_h = fp16( dinv * relu(hn@W1+b1) @ W2 ) ----------------

#define MLP_TILES ((N_NODES + 63) / 64)   // 1563
#define MLP_GRID 512
#define LDW 136                            // padded row stride (bf16) -> 2-way banks, free

__global__ __launch_bounds__(256) void k_mlp(const uint* __restrict__ hb16,
                                             const float* __restrict__ W1,
                                             const float* __restrict__ b1,
                                             const float* __restrict__ W2,
                                             const float* __restrict__ dinv,
                                             __half* __restrict__ xws_h) {
    __shared__ ushort sW1T[128 * LDW];   // W1^T bf16: [n][k], 34 KB
    __shared__ ushort sW2T[48 * LDW];    // W2^T bf16: [n][k], cols 40..47 zero, 12.75 KB
    __shared__ ushort sA[64 * LDW];      // hn tile / then h tile, 17 KB
    __shared__ float sb1[128];
    int t = threadIdx.x;

    for (int i = t; i < 128 * 128; i += 256) {
        int k = i >> 7, nn = i & 127;
        sW1T[nn * LDW + k] = f2bf(W1[i]);
    }
    for (int i = t; i < 48 * LDW; i += 256) sW2T[i] = 0;
    if (t < 128) sb1[t] = b1[t];
    __syncthreads();
    for (int i = t; i < 128 * C_DIM; i += 256) {
        int k = i / C_DIM, nn = i - k * C_DIM;
        sW2T[nn * LDW + k] = f2bf(W2[i]);
    }

    int wv = t >> 6, l = t & 63;
    int lr = l & 15, quad = l >> 4;

    for (int tile = blockIdx.x; tile < MLP_TILES; tile += MLP_GRID) {
        int rowbase = tile * 64;
        __syncthreads();   // protect sA from previous iteration readers
        for (int i = t; i < 1024; i += 256) {
            int r = i >> 4, c = i & 15;     // c: uint4 index within row (16 B = 8 bf16)
            uint4 v = make_uint4(0, 0, 0, 0);
            if (rowbase + r < N_NODES)
                v = ((const uint4*)hb16)[(size_t)(rowbase + r) * 16 + c];
            *(uint4*)&sA[r * LDW + c * 8] = v;
        }
        __syncthreads();

        // ---- GEMM1: h = relu(hn @ W1 + b1), stay in this wave's 16 rows ----
        bf16x8 af[4];
#pragma unroll
        for (int kk = 0; kk < 4; kk++)
            af[kk] = *(const bf16x8*)&sA[(wv * 16 + lr) * LDW + kk * 32 + quad * 8];

        f32x4 acc[8];
#pragma unroll
        for (int ct = 0; ct < 8; ct++) {
            acc[ct] = (f32x4){0.f, 0.f, 0.f, 0.f};
#pragma unroll
            for (int kk = 0; kk < 4; kk++) {
                bf16x8 bf = *(const bf16x8*)&sW1T[(ct * 16 + lr) * LDW + kk * 32 + quad * 8];
                acc[ct] = __builtin_amdgcn_mfma_f32_16x16x32_bf16(af[kk], bf, acc[ct], 0, 0, 0);
            }
        }
#pragma unroll
        for (int ct = 0; ct < 8; ct++) {
            float bb = sb1[ct * 16 + lr];
#pragma unroll
            for (int r = 0; r < 4; r++) {
                float hv = fmaxf(acc[ct][r] + bb, 0.0f);
                sA[(wv * 16 + quad * 4 + r) * LDW + ct * 16 + lr] = f2bf(hv);
            }
        }
        // ---- GEMM2: xws = dinv * (h @ W2) ---- (same wave's rows: LDS in-order, no barrier)
        bf16x8 hf[4];
#pragma unroll
        for (int kk = 0; kk < 4; kk++)
            hf[kk] = *(const bf16x8*)&sA[(wv * 16 + lr) * LDW + kk * 32 + quad * 8];

        float dv[4];
#pragma unroll
        for (int r = 0; r < 4; r++) {
            int grow = rowbase + wv * 16 + quad * 4 + r;
            dv[r] = (grow < N_NODES) ? dinv[grow] : 0.0f;
        }
#pragma unroll
        for (int ct2 = 0; ct2 < 3; ct2++) {
            f32x4 acc2 = (f32x4){0.f, 0.f, 0.f, 0.f};
#pragma unroll
            for (int kk = 0; kk < 4; kk++) {
                bf16x8 bf = *(const bf16x8*)&sW2T[(ct2 * 16 + lr) * LDW + kk * 32 + quad * 8];
                acc2 = __builtin_amdgcn_mfma_f32_16x16x32_bf16(hf[kk], bf, acc2, 0, 0, 0);
            }
            int nn = ct2 * 16 + lr;
            if (nn < C_DIM) {
#pragma unroll
                for (int r = 0; r < 4; r++) {
                    int grow = rowbase + wv * 16 + quad * 4 + r;
                    if (grow < N_NODES)
                        xws_h[(size_t)grow * C_DIM + nn] = __float2half(acc2[r] * dv[r]);
                }
            }
        }
    }
}

// ---------------- GCN conv + bias + log_softmax: dual-node half-wave gather ----------------
// (round-7 structure — measured win, unchanged)

#define G_GCN (N_NODES / 8)   // 12500 blocks, 8 nodes each

__global__ __launch_bounds__(256) void k_gcn(const __half* __restrict__ xws_h,
                                             const float* __restrict__ dinv,
                                             const int* __restrict__ scol,
                                             const int* __restrict__ off, const int* __restrict__ cnt,
                                             const float* __restrict__ b2,
                                             float* __restrict__ out) {
    int wv = threadIdx.x >> 6;
    int widA = blockIdx.x * 8 + wv * 2;   // < N_NODES always (grid exact)
    int widB = widA + 1;                   // < N_NODES always
    int l = threadIdx.x & 63;
    int lh = l & 31;
    bool isB = l >= 32;
    bool act = lh < (C_DIM / 2);          // lanes lh 0..19 own classes 2lh, 2lh+1
    int ll = act ? lh : 0;

    int sA = RFL(off[widA]); int lA = RFL(cnt[widA]);
    int sB = RFL(off[widB]); int lB = RFL(cnt[widB]);
    float dA = dinv[widA];
    float dB = dinv[widB];
    int jmax = max(lA, lB);
    const char* xb = (const char*)xws_h;
    uint lby = (uint)ll * 4u;             // byte offset of this lane's uint within the 80-B row

    float s0 = 0.f, s1 = 0.f, s2 = 0.f, s3 = 0.f;
    float s4 = 0.f, s5 = 0.f, s6 = 0.f, s7 = 0.f;

    for (int j = 0; j < jmax; j += 8) {
        uint oa[8], ob[8];
#pragma unroll
        for (int k = 0; k < 8; k++) {
            int ca = RFL(scol[sA + j + k]);
            int cb = RFL(scol[sB + j + k]);
            oa[k] = (j + k < lA) ? (uint)(ca * (C_DIM * 2)) : ZOFFW;   // s_cselect
            ob[k] = (j + k < lB) ? (uint)(cb * (C_DIM * 2)) : ZOFFW;
        }
#pragma unroll
        for (int k = 0; k < 8; k += 4) {
            uint u0 = *(const uint*)(xb + ((isB ? ob[k + 0] : oa[k + 0]) + lby));
            uint u1 = *(const uint*)(xb + ((isB ? ob[k + 1] : oa[k + 1]) + lby));
            uint u2 = *(const uint*)(xb + ((isB ? ob[k + 2] : oa[k + 2]) + lby));
            uint u3 = *(const uint*)(xb + ((isB ? ob[k + 3] : oa[k + 3]) + lby));
            acc_xy(u0, s0, s1);
            acc_xy(u1, s2, s3);
            acc_xy(u2, s4, s5);
            acc_xy(u3, s6, s7);
        }
    }

    // self term (GCN self-loop) for this lane's node
    uint us = *(const uint*)(xb + ((isB ? (uint)(widB * (C_DIM * 2)) : (uint)(widA * (C_DIM * 2))) + lby));
    float sx = (s0 + s2) + (s4 + s6);
    float sy = (s1 + s3) + (s5 + s7);
    acc_xy(us, sx, sy);

    float di = isB ? dB : dA;
    float2 bb = act ? ((const float2*)b2)[ll] : make_float2(0.f, 0.f);
    float val0 = di * sx + bb.x;
    float val1 = di * sy + bb.y;

    // softmax within each 32-lane half (offsets <= 16 keep exchanges inside the half)
    float m = act ? fmaxf(val0, val1) : -1e30f;
#pragma unroll
    for (int o = 16; o > 0; o >>= 1) m = fmaxf(m, __shfl_xor(m, o, 64));
    float e = act ? (__expf(val0 - m) + __expf(val1 - m)) : 0.0f;
#pragma unroll
    for (int o = 16; o > 0; o >>= 1) e += __shfl_xor(e, o, 64);
    if (act) {
        float lse = m + __logf(e);
        int wid = isB ? widB : widA;
        float2 o2 = make_float2(val0 - lse, val1 - lse);
        ((float2*)out)[(size_t)wid * 20 + lh] = o2;
    }
}

// ---------------- launch ----------------

extern "C" void kernel_launch(void* const* d_in, const int* in_sizes, int n_in,
                              void* d_out, int out_size, void* d_ws, size_t ws_size,
                              hipStream_t stream) {
    const float* x = (const float*)d_in[0];
    const int* mask = (const int*)d_in[1];
    const int* eidx = (const int*)d_in[2];
    const float* W1 = (const float*)d_in[3];
    const float* b1 = (const float*)d_in[4];
    const float* W2 = (const float*)d_in[5];
    const float* b2 = (const float*)d_in[6];
    float* out = (float*)d_out;

    const int* row = eidx;
    const int* col = eidx + N_EDGES;

    char* base = (char*)d_ws;
    size_t o = 0;
    auto alloc = [&](size_t bytes) {
        void* p = base + o;
        o = (o + bytes + 255) & ~(size_t)255;
        return p;
    };
    int* cnt = (int*)alloc(N_NODES * 4);        // per-row degree (built by k_prep atomics)
    int* off = (int*)alloc(N_NODES * 4);
    float* dinv = (float*)alloc(N_NODES * 4);
    int* gfill = (int*)alloc(N_NODES * 4);
    int* bcnt = (int*)alloc(NBUCK * 4);
    int* bbase = (int*)alloc((NBUCK + 1) * 4);
    int* scol = (int*)alloc(N_EDGES * 4);
    __half* xh = (__half*)alloc((size_t)N_NODES * F_DIM * 2);
    uint* hb16 = (uint*)alloc((size_t)N_NODES * F_DIM * 2);
    __half* xws_h = (__half*)alloc((size_t)(N_NODES + 1) * C_DIM * 2);   // +1 zero row for k_gcn clamp
    (void)ws_size;

    hipMemsetAsync(bcnt, 0, NBUCK * 4, stream);
    hipMemsetAsync(cnt, 0, N_NODES * 4, stream);
    hipMemsetAsync(xws_h + (size_t)ZROW * C_DIM, 0, C_DIM * 2, stream);  // zero gather row

    k_prep<<<NBLK_BUCKET + G_NODE, 256, 0, stream>>>(row, mask, x, bcnt, cnt, xh);
    k_bscan<<<1, 256, 0, stream>>>(bcnt, bbase);
    k_rowoff<<<NBUCK, 128, 0, stream>>>(cnt, bbase, off, dinv, gfill);
    k_place<<<(N_EDGES + 255) / 256, 256, 0, stream>>>(row, col, gfill, scol);
    k_agg<<<G_NODE, 256, 0, stream>>>(xh, scol, off, cnt, hb16);
    k_mlp<<<MLP_GRID, 256, 0, stream>>>(hb16, W1, b1, W2, dinv, xws_h);
    k_gcn<<<G_GCN, 256, 0, stream>>>(xws_h, dinv, scol, off, cnt, b2, out);
}

// Round 9
// 310.058 us; speedup vs baseline: 1.3571x; 1.3571x over previous
//
#include <hip/hip_runtime.h>
#include <hip/hip_fp16.h>
#include <math.h>

#define N_NODES 100000
#define N_EDGES 1600000
#define F_DIM 128
#define C_DIM 40
#define ZROW N_NODES                      // index of the all-zero xws row (gather clamp target)
#define ZOFFW ((uint)(ZROW * C_DIM * 4 / 2))   // byte offset of zero row in xws_h (80-B rows)

#define NBUCK 782            // ceil(100000 / 128) row-buckets of 128 rows
#define EB 4096              // edges per bucket-phase block
#define NBLK_BUCKET ((N_EDGES + EB - 1) / EB)   // 391
#define BCAP 4096            // k_bsort LDS staging capacity (mean bucket ~2046)

typedef unsigned long long ull;
typedef unsigned int uint;
typedef unsigned short ushort;

typedef __attribute__((ext_vector_type(8))) short bf16x8;
typedef __attribute__((ext_vector_type(4))) float f32x4;

__device__ __forceinline__ ushort f2bf(float f) {   // fp32 -> bf16 bits, RNE
    uint u = __float_as_uint(f);
    uint r = u + 0x7FFFu + ((u >> 16) & 1u);
    return (ushort)(r >> 16);
}

// fp16-pair accumulate: ax += h.x, ay += h.y (fp32 accumulation)
#if __has_builtin(__builtin_amdgcn_fdot2)
typedef __attribute__((ext_vector_type(2))) _Float16 h2f;
__device__ __forceinline__ void acc_xy(uint u, float& ax, float& ay) {
    union { uint u; h2f h; } z; z.u = u;
    union { uint u; h2f h; } ox; ox.u = 0x00003C00u;   // (1.0h, 0.0h)
    union { uint u; h2f h; } oy; oy.u = 0x3C000000u;   // (0.0h, 1.0h)
    ax = __builtin_amdgcn_fdot2(z.h, ox.h, ax, false);
    ay = __builtin_amdgcn_fdot2(z.h, oy.h, ay, false);
}
#else
__device__ __forceinline__ void acc_xy(uint u, float& ax, float& ay) {
    float2 v = __half22float2(*reinterpret_cast<__half2*>(&u));
    ax += v.x; ay += v.y;
}
#endif

__device__ __forceinline__ void cnt_xy(uint u, int& ix, int& iy) {
    ix += (u & 0xffffu) ? 1 : 0;
    iy += (u >> 16) ? 1 : 0;
}

#define RFL(v) __builtin_amdgcn_readfirstlane(v)

// ---------------- init: replaces all hipMemsetAsync (1 launch instead of 2 DMAs) ----------------

__global__ __launch_bounds__(256) void k_init(int* __restrict__ bcnt,
                                              int* __restrict__ bfill,
                                              __half* __restrict__ xws_h) {
    int t = threadIdx.x;
    for (int i = t; i < NBUCK; i += 256) { bcnt[i] = 0; bfill[i] = 0; }
    if (t < C_DIM) xws_h[(size_t)ZROW * C_DIM + t] = __float2half(0.0f);
}

// ---------------- fused prep: LDS bucket histogram + x -> premasked nonzero-encoded fp16 ----------------
// Encoding: masked-out -> 0x0000 exactly; observed -> fp16(x), +0.0 forced to minimal
// subnormal so "observed" <=> bits != 0.

#define G_NODE ((N_NODES + 3) / 4)         // 25000 (wave per node)

__global__ __launch_bounds__(256) void k_prep(const int* __restrict__ row,
                                              const int* __restrict__ mask,
                                              const float* __restrict__ x,
                                              int* __restrict__ bcnt,
                                              __half* __restrict__ xh) {
    if (blockIdx.x < NBLK_BUCKET) {
        __shared__ int lh[NBUCK];
        int t = threadIdx.x;
        int base = blockIdx.x * EB;
        int cnt = min(EB, N_EDGES - base);
        for (int i = t; i < NBUCK; i += 256) lh[i] = 0;
        __syncthreads();
        for (int i = t; i < cnt; i += 256)
            atomicAdd(&lh[row[base + i] >> 7], 1);
        __syncthreads();
        for (int b = t; b < NBUCK; b += 256) {
            int c = lh[b];
            if (c) atomicAdd(&bcnt[b], c);
        }
        return;
    }
    int nb = blockIdx.x - NBLK_BUCKET;
    int wv = threadIdx.x >> 6;
    int l = threadIdx.x & 63;
    int wid = nb * 4 + wv;                 // < 100000 exactly
    // lane owns feature pair (2l, 2l+1)
    int2 m2 = ((const int2*)mask)[(size_t)wid * 64 + l];
    float2 x2 = ((const float2*)x)[(size_t)wid * 64 + l];
    ushort e0 = 0, e1 = 0;
    if (m2.x) { e0 = __half_as_ushort(__float2half(x2.x)); if (e0 == 0) e0 = 1; }
    if (m2.y) { e1 = __half_as_ushort(__float2half(x2.y)); if (e1 == 0) e1 = 1; }
    ((uint*)xh)[(size_t)wid * 64 + l] = (uint)e0 | ((uint)e1 << 16);
}

// ---------------- CSR build phase A: counting sort into coarse buckets ----------------
// k_bscan is absorbed: each block computes the 782-bucket exclusive prefix of bcnt
// in-LDS (bcnt is final after k_prep; 3 KB L2-hot read, parallel across 391 blocks).
// bfill is a RELATIVE fill counter (zeroed by k_init); block 0 publishes bbase for k_bsort.

__global__ __launch_bounds__(256) void k_bucket(const int* __restrict__ row,
                                                const int* __restrict__ col,
                                                const int* __restrict__ bcnt,
                                                int* __restrict__ bfill,
                                                int* __restrict__ bbase_g,
                                                ull* __restrict__ ebuf) {
    __shared__ int lhist[1024];
    __shared__ int lscan[1024];
    __shared__ int bbase_s[NBUCK + 1];
    __shared__ int gbase[NBUCK];
    __shared__ ull stage[EB];       // 32 KB
    __shared__ int partial[256];
    int t = threadIdx.x;
    int base = blockIdx.x * EB;
    int cnt = min(EB, N_EDGES - base);
    int b4 = t * 4;

    // ---- global bucket prefix (replaces k_bscan) ----
    {
        int v0 = (b4 + 0 < NBUCK) ? bcnt[b4 + 0] : 0;
        int v1 = (b4 + 1 < NBUCK) ? bcnt[b4 + 1] : 0;
        int v2 = (b4 + 2 < NBUCK) ? bcnt[b4 + 2] : 0;
        int v3 = (b4 + 3 < NBUCK) ? bcnt[b4 + 3] : 0;
        int s0 = v0, s1 = s0 + v1, s2 = s1 + v2, s3 = s2 + v3;
        partial[t] = s3;
        __syncthreads();
        for (int d = 1; d < 256; d <<= 1) {
            int xv = (t >= d) ? partial[t - d] : 0;
            __syncthreads();
            partial[t] += xv;
            __syncthreads();
        }
        int excl = partial[t] - s3;
        if (b4 + 0 < NBUCK) bbase_s[b4 + 0] = excl;
        if (b4 + 1 < NBUCK) bbase_s[b4 + 1] = excl + s0;
        if (b4 + 2 < NBUCK) bbase_s[b4 + 2] = excl + s1;
        if (b4 + 3 < NBUCK) bbase_s[b4 + 3] = excl + s2;
        if (t == 255) bbase_s[NBUCK] = partial[255];   // == N_EDGES
    }

    for (int i = t; i < 1024; i += 256) lhist[i] = 0;
    __syncthreads();
    for (int i = t; i < cnt; i += 256)
        atomicAdd(&lhist[row[base + i] >> 7], 1);
    __syncthreads();

    int h0 = lhist[b4], h1 = lhist[b4 + 1], h2 = lhist[b4 + 2], h3 = lhist[b4 + 3];
    int s3l = h0 + h1 + h2 + h3;
    partial[t] = s3l;
    __syncthreads();
    for (int d = 1; d < 256; d <<= 1) {
        int xv = (t >= d) ? partial[t - d] : 0;
        __syncthreads();
        partial[t] += xv;
        __syncthreads();
    }
    int excl2 = partial[t] - s3l;
    lscan[b4] = excl2;
    lscan[b4 + 1] = excl2 + h0;
    lscan[b4 + 2] = excl2 + h0 + h1;
    lscan[b4 + 3] = excl2 + h0 + h1 + h2;
    __syncthreads();

    for (int i = t; i < 1024; i += 256) lhist[i] = 0;
    __syncthreads();

    for (int i = t; i < cnt; i += 256) {
        int r = row[base + i];
        int c = col[base + i];
        int b = r >> 7;
        int p = lscan[b] + atomicAdd(&lhist[b], 1);
        stage[p] = ((ull)(unsigned)c << 32) | (unsigned)r;
    }
    __syncthreads();

    for (int b = t; b < NBUCK; b += 256) {
        int c = lhist[b];
        gbase[b] = c ? (bbase_s[b] + atomicAdd(&bfill[b], c)) : 0;
    }
    __syncthreads();

    for (int i = t; i < cnt; i += 256) {
        ull pk = stage[i];
        int b = ((int)(unsigned)(pk & 0xffffffffull)) >> 7;
        int dst = gbase[b] + (i - lscan[b]);
        ebuf[dst] = pk;
    }

    if (blockIdx.x == 0)
        for (int i = t; i <= NBUCK; i += 256) bbase_g[i] = bbase_s[i];
}

// ---------------- CSR phase B: in-bucket sort + per-row degree/offset/dinv ----------------

__global__ __launch_bounds__(256) void k_bsort(const ull* __restrict__ ebuf,
                                               const int* __restrict__ bbase,
                                               int* __restrict__ off, int* __restrict__ cnt,
                                               float* __restrict__ dinv,
                                               int* __restrict__ scol) {
    __shared__ ull stage[BCAP];     // 32 KB
    __shared__ int lcol[BCAP];      // 16 KB
    __shared__ int lrc[128];
    __shared__ int lexcl[128];
    __shared__ int lfill[128];
    int b = blockIdx.x;
    int rowbase = b << 7;
    int segstart = bbase[b];
    int m = bbase[b + 1] - segstart;
    int t = threadIdx.x;

    if (t < 128) lrc[t] = 0;
    __syncthreads();
    for (int i = t; i < m; i += 256) {
        ull pk = ebuf[segstart + i];
        if (i < BCAP) stage[i] = pk;
        atomicAdd(&lrc[(int)(unsigned)(pk & 0xffffffffull) & 127], 1);
    }
    __syncthreads();
    if (t < 128) lexcl[t] = lrc[t];
    __syncthreads();
    for (int d = 1; d < 128; d <<= 1) {
        int xv = (t >= d && t < 128) ? lexcl[t - d] : 0;
        __syncthreads();
        if (t < 128) lexcl[t] += xv;
        __syncthreads();
    }
    if (t < 128) {
        int excl = lexcl[t] - lrc[t];
        lfill[t] = excl;
        int r = rowbase + t;
        if (r < N_NODES) {
            off[r] = segstart + excl;
            cnt[r] = lrc[t];
            dinv[r] = rsqrtf((float)lrc[t] + 1.0f);
        }
    }
    __syncthreads();
    for (int i = t; i < m; i += 256) {
        ull pk = (i < BCAP) ? stage[i] : ebuf[segstart + i];
        int r = (int)(unsigned)(pk & 0xffffffffull);
        int c = (int)(unsigned)(pk >> 32);
        int p = atomicAdd(&lfill[r & 127], 1);
        if (p < BCAP) lcol[p] = c;
        else scol[segstart + p] = c;
    }
    __syncthreads();
    int mm = m < BCAP ? m : BCAP;
    for (int i = t; i < mm; i += 256) scol[segstart + i] = lcol[i];
}

// ---------------- PaGNN masked-mean aggregation: wave/node, scalar ids, SGPR-base gather ----------------
// (round-0 structure — measured 57.2/57.0 us, at the L2-miss-path floor for 256-B rows)

__global__ __launch_bounds__(256) void k_agg(const __half* __restrict__ xh,
                                             const int* __restrict__ scol,
                                             const int* __restrict__ off, const int* __restrict__ cnt,
                                             uint* __restrict__ hb16) {
    int wv = threadIdx.x >> 6;
    int wid = blockIdx.x * 4 + wv;
    int l = threadIdx.x & 63;
    if (wid >= N_NODES) return;
    int swid = RFL(wid);
    int sstart = RFL(off[swid]);
    int slen = RFL(cnt[swid]);
    const uint* xu = (const uint*)xh;   // index: node*64 + l  (features 2l, 2l+1)

    float ax0 = 0.f, ay0 = 0.f, ax1 = 0.f, ay1 = 0.f;
    float ax2 = 0.f, ay2 = 0.f, ax3 = 0.f, ay3 = 0.f;
    int ix0 = 0, iy0 = 0, ix1 = 0, iy1 = 0;
    int ix2 = 0, iy2 = 0, ix3 = 0, iy3 = 0;

    int j = 0;
    for (; j + 8 <= slen; j += 8) {
        int c0 = RFL(scol[sstart + j + 0]);
        int c1 = RFL(scol[sstart + j + 1]);
        int c2 = RFL(scol[sstart + j + 2]);
        int c3 = RFL(scol[sstart + j + 3]);
        int c4 = RFL(scol[sstart + j + 4]);
        int c5 = RFL(scol[sstart + j + 5]);
        int c6 = RFL(scol[sstart + j + 6]);
        int c7 = RFL(scol[sstart + j + 7]);
        uint u0 = xu[(size_t)c0 * 64 + l];
        uint u1 = xu[(size_t)c1 * 64 + l];
        uint u2 = xu[(size_t)c2 * 64 + l];
        uint u3 = xu[(size_t)c3 * 64 + l];
        uint u4 = xu[(size_t)c4 * 64 + l];
        uint u5 = xu[(size_t)c5 * 64 + l];
        uint u6 = xu[(size_t)c6 * 64 + l];
        uint u7 = xu[(size_t)c7 * 64 + l];
        acc_xy(u0, ax0, ay0); cnt_xy(u0, ix0, iy0);
        acc_xy(u1, ax1, ay1); cnt_xy(u1, ix1, iy1);
        acc_xy(u2, ax2, ay2); cnt_xy(u2, ix2, iy2);
        acc_xy(u3, ax3, ay3); cnt_xy(u3, ix3, iy3);
        acc_xy(u4, ax0, ay0); cnt_xy(u4, ix0, iy0);
        acc_xy(u5, ax1, ay1); cnt_xy(u5, ix1, iy1);
        acc_xy(u6, ax2, ay2); cnt_xy(u6, ix2, iy2);
        acc_xy(u7, ax3, ay3); cnt_xy(u7, ix3, iy3);
    }
    for (; j + 4 <= slen; j += 4) {
        int c0 = RFL(scol[sstart + j + 0]);
        int c1 = RFL(scol[sstart + j + 1]);
        int c2 = RFL(scol[sstart + j + 2]);
        int c3 = RFL(scol[sstart + j + 3]);
        uint u0 = xu[(size_t)c0 * 64 + l];
        uint u1 = xu[(size_t)c1 * 64 + l];
        uint u2 = xu[(size_t)c2 * 64 + l];
        uint u3 = xu[(size_t)c3 * 64 + l];
        acc_xy(u0, ax0, ay0); cnt_xy(u0, ix0, iy0);
        acc_xy(u1, ax1, ay1); cnt_xy(u1, ix1, iy1);
        acc_xy(u2, ax2, ay2); cnt_xy(u2, ix2, iy2);
        acc_xy(u3, ax3, ay3); cnt_xy(u3, ix3, iy3);
    }
    for (; j < slen; j++) {
        int c0 = RFL(scol[sstart + j]);
        uint u0 = xu[(size_t)c0 * 64 + l];
        acc_xy(u0, ax0, ay0); cnt_xy(u0, ix0, iy0);
    }

    float ax = (ax0 + ax1) + (ax2 + ax3);
    float ay = (ay0 + ay1) + (ay2 + ay3);
    float dx = (float)((ix0 + ix1) + (ix2 + ix3));
    float dy = (float)((iy0 + iy1) + (iy2 + iy3));
    float hx = ax / fmaxf(dx, 1.0f);
    float hy = ay / fmaxf(dy, 1.0f);
    hb16[(size_t)wid * 64 + l] = (uint)f2bf(hx) | ((uint)f2bf(hy) << 16);
}

// ---------------- fused MLP (persistent MFMA): xws_h = fp16( dinv * relu(hn@W1+b1) @ W2 ) ----------------

#define MLP_TILES ((N_NODES + 63) / 64)   // 1563
#define MLP_GRID 512
#define LDW 136                            // padded row stride (bf16) -> 2-way banks, free

__global__ __launch_bounds__(256) void k_mlp(const uint* __restrict__ hb16,
                                             const float* __restrict__ W1,
                                             const float* __restrict__ b1,
                                             const float* __restrict__ W2,
                                             const float* __restrict__ dinv,
                                             __half* __restrict__ xws_h) {
    __shared__ ushort sW1T[128 * LDW];   // W1^T bf16: [n][k], 34 KB
    __shared__ ushort sW2T[48 * LDW];    // W2^T bf16: [n][k], cols 40..47 zero, 12.75 KB
    __shared__ ushort sA[64 * LDW];      // hn tile / then h tile, 17 KB
    __shared__ float sb1[128];
    int t = threadIdx.x;

    for (int i = t; i < 128 * 128; i += 256) {
        int k = i >> 7, nn = i & 127;
        sW1T[nn * LDW + k] = f2bf(W1[i]);
    }
    for (int i = t; i < 48 * LDW; i += 256) sW2T[i] = 0;
    if (t < 128) sb1[t] = b1[t];
    __syncthreads();
    for (int i = t; i < 128 * C_DIM; i += 256) {
        int k = i / C_DIM, nn = i - k * C_DIM;
        sW2T[nn * LDW + k] = f2bf(W2[i]);
    }

    int wv = t >> 6, l = t & 63;
    int lr = l & 15, quad = l >> 4;

    for (int tile = blockIdx.x; tile < MLP_TILES; tile += MLP_GRID) {
        int rowbase = tile * 64;
        __syncthreads();   // protect sA from previous iteration readers
        for (int i = t; i < 1024; i += 256) {
            int r = i >> 4, c = i & 15;     // c: uint4 index within row (16 B = 8 bf16)
            uint4 v = make_uint4(0, 0, 0, 0);
            if (rowbase + r < N_NODES)
                v = ((const uint4*)hb16)[(size_t)(rowbase + r) * 16 + c];
            *(uint4*)&sA[r * LDW + c * 8] = v;
        }
        __syncthreads();

        // ---- GEMM1: h = relu(hn @ W1 + b1), stay in this wave's 16 rows ----
        bf16x8 af[4];
#pragma unroll
        for (int kk = 0; kk < 4; kk++)
            af[kk] = *(const bf16x8*)&sA[(wv * 16 + lr) * LDW + kk * 32 + quad * 8];

        f32x4 acc[8];
#pragma unroll
        for (int ct = 0; ct < 8; ct++) {
            acc[ct] = (f32x4){0.f, 0.f, 0.f, 0.f};
#pragma unroll
            for (int kk = 0; kk < 4; kk++) {
                bf16x8 bf = *(const bf16x8*)&sW1T[(ct * 16 + lr) * LDW + kk * 32 + quad * 8];
                acc[ct] = __builtin_amdgcn_mfma_f32_16x16x32_bf16(af[kk], bf, acc[ct], 0, 0, 0);
            }
        }
#pragma unroll
        for (int ct = 0; ct < 8; ct++) {
            float bb = sb1[ct * 16 + lr];
#pragma unroll
            for (int r = 0; r < 4; r++) {
                float hv = fmaxf(acc[ct][r] + bb, 0.0f);
                sA[(wv * 16 + quad * 4 + r) * LDW + ct * 16 + lr] = f2bf(hv);
            }
        }
        // ---- GEMM2: xws = dinv * (h @ W2) ---- (same wave's rows: LDS in-order, no barrier)
        bf16x8 hf[4];
#pragma unroll
        for (int kk = 0; kk < 4; kk++)
            hf[kk] = *(const bf16x8*)&sA[(wv * 16 + lr) * LDW + kk * 32 + quad * 8];

        float dv[4];
#pragma unroll
        for (int r = 0; r < 4; r++) {
            int grow = rowbase + wv * 16 + quad * 4 + r;
            dv[r] = (grow < N_NODES) ? dinv[grow] : 0.0f;
        }
#pragma unroll
        for (int ct2 = 0; ct2 < 3; ct2++) {
            f32x4 acc2 = (f32x4){0.f, 0.f, 0.f, 0.f};
#pragma unroll
            for (int kk = 0; kk < 4; kk++) {
                bf16x8 bf = *(const bf16x8*)&sW2T[(ct2 * 16 + lr) * LDW + kk * 32 + quad * 8];
                acc2 = __builtin_amdgcn_mfma_f32_16x16x32_bf16(hf[kk], bf, acc2, 0, 0, 0);
            }
            int nn = ct2 * 16 + lr;
            if (nn < C_DIM) {
#pragma unroll
                for (int r = 0; r < 4; r++) {
                    int grow = rowbase + wv * 16 + quad * 4 + r;
                    if (grow < N_NODES)
                        xws_h[(size_t)grow * C_DIM + nn] = __float2half(acc2[r] * dv[r]);
                }
            }
        }
    }
}

// ---------------- GCN conv + bias + log_softmax: dual-node half-wave gather ----------------
// (round-7 structure — measured win, unchanged)

#define G_GCN (N_NODES / 8)   // 12500 blocks, 8 nodes each

__global__ __launch_bounds__(256) void k_gcn(const __half* __restrict__ xws_h,
                                             const float* __restrict__ dinv,
                                             const int* __restrict__ scol,
                                             const int* __restrict__ off, const int* __restrict__ cnt,
                                             const float* __restrict__ b2,
                                             float* __restrict__ out) {
    int wv = threadIdx.x >> 6;
    int widA = blockIdx.x * 8 + wv * 2;   // < N_NODES always (grid exact)
    int widB = widA + 1;                   // < N_NODES always
    int l = threadIdx.x & 63;
    int lh = l & 31;
    bool isB = l >= 32;
    bool act = lh < (C_DIM / 2);          // lanes lh 0..19 own classes 2lh, 2lh+1
    int ll = act ? lh : 0;

    int sA = RFL(off[widA]); int lA = RFL(cnt[widA]);
    int sB = RFL(off[widB]); int lB = RFL(cnt[widB]);
    float dA = dinv[widA];
    float dB = dinv[widB];
    int jmax = max(lA, lB);
    const char* xb = (const char*)xws_h;
    uint lby = (uint)ll * 4u;             // byte offset of this lane's uint within the 80-B row

    float s0 = 0.f, s1 = 0.f, s2 = 0.f, s3 = 0.f;
    float s4 = 0.f, s5 = 0.f, s6 = 0.f, s7 = 0.f;

    for (int j = 0; j < jmax; j += 8) {
        uint oa[8], ob[8];
#pragma unroll
        for (int k = 0; k < 8; k++) {
            int ca = RFL(scol[sA + j + k]);
            int cb = RFL(scol[sB + j + k]);
            oa[k] = (j + k < lA) ? (uint)(ca * (C_DIM * 2)) : ZOFFW;   // s_cselect
            ob[k] = (j + k < lB) ? (uint)(cb * (C_DIM * 2)) : ZOFFW;
        }
#pragma unroll
        for (int k = 0; k < 8; k += 4) {
            uint u0 = *(const uint*)(xb + ((isB ? ob[k + 0] : oa[k + 0]) + lby));
            uint u1 = *(const uint*)(xb + ((isB ? ob[k + 1] : oa[k + 1]) + lby));
            uint u2 = *(const uint*)(xb + ((isB ? ob[k + 2] : oa[k + 2]) + lby));
            uint u3 = *(const uint*)(xb + ((isB ? ob[k + 3] : oa[k + 3]) + lby));
            acc_xy(u0, s0, s1);
            acc_xy(u1, s2, s3);
            acc_xy(u2, s4, s5);
            acc_xy(u3, s6, s7);
        }
    }

    // self term (GCN self-loop) for this lane's node
    uint us = *(const uint*)(xb + ((isB ? (uint)(widB * (C_DIM * 2)) : (uint)(widA * (C_DIM * 2))) + lby));
    float sx = (s0 + s2) + (s4 + s6);
    float sy = (s1 + s3) + (s5 + s7);
    acc_xy(us, sx, sy);

    float di = isB ? dB : dA;
    float2 bb = act ? ((const float2*)b2)[ll] : make_float2(0.f, 0.f);
    float val0 = di * sx + bb.x;
    float val1 = di * sy + bb.y;

    // softmax within each 32-lane half (offsets <= 16 keep exchanges inside the half)
    float m = act ? fmaxf(val0, val1) : -1e30f;
#pragma unroll
    for (int o = 16; o > 0; o >>= 1) m = fmaxf(m, __shfl_xor(m, o, 64));
    float e = act ? (__expf(val0 - m) + __expf(val1 - m)) : 0.0f;
#pragma unroll
    for (int o = 16; o > 0; o >>= 1) e += __shfl_xor(e, o, 64);
    if (act) {
        float lse = m + __logf(e);
        int wid = isB ? widB : widA;
        float2 o2 = make_float2(val0 - lse, val1 - lse);
        ((float2*)out)[(size_t)wid * 20 + lh] = o2;
    }
}

// ---------------- launch ----------------

extern "C" void kernel_launch(void* const* d_in, const int* in_sizes, int n_in,
                              void* d_out, int out_size, void* d_ws, size_t ws_size,
                              hipStream_t stream) {
    const float* x = (const float*)d_in[0];
    const int* mask = (const int*)d_in[1];
    const int* eidx = (const int*)d_in[2];
    const float* W1 = (const float*)d_in[3];
    const float* b1 = (const float*)d_in[4];
    const float* W2 = (const float*)d_in[5];
    const float* b2 = (const float*)d_in[6];
    float* out = (float*)d_out;

    const int* row = eidx;
    const int* col = eidx + N_EDGES;

    char* base = (char*)d_ws;
    size_t o = 0;
    auto alloc = [&](size_t bytes) {
        void* p = base + o;
        o = (o + bytes + 255) & ~(size_t)255;
        return p;
    };
    int* cnt = (int*)alloc(N_NODES * 4);
    int* off = (int*)alloc(N_NODES * 4);
    float* dinv = (float*)alloc(N_NODES * 4);
    int* bcnt = (int*)alloc(NBUCK * 4);
    int* bfill = (int*)alloc(NBUCK * 4);
    int* bbase = (int*)alloc((NBUCK + 1) * 4);
    int* scol = (int*)alloc(N_EDGES * 4);
    __half* xh = (__half*)alloc((size_t)N_NODES * F_DIM * 2);
    uint* hb16 = (uint*)alloc((size_t)N_NODES * F_DIM * 2);
    __half* xws_h = (__half*)alloc((size_t)(N_NODES + 1) * C_DIM * 2);   // +1 zero row for k_gcn clamp
    (void)ws_size;

    ull* ebuf = (ull*)hb16;   // alias: ebuf (12.8 MB) dead before k_agg writes hb16 (25.6 MB)

    k_init<<<1, 256, 0, stream>>>(bcnt, bfill, xws_h);
    k_prep<<<NBLK_BUCKET + G_NODE, 256, 0, stream>>>(row, mask, x, bcnt, xh);
    k_bucket<<<NBLK_BUCKET, 256, 0, stream>>>(row, col, bcnt, bfill, bbase, ebuf);
    k_bsort<<<NBUCK, 256, 0, stream>>>(ebuf, bbase, off, cnt, dinv, scol);
    k_agg<<<G_NODE, 256, 0, stream>>>(xh, scol, off, cnt, hb16);
    k_mlp<<<MLP_GRID, 256, 0, stream>>>(hb16, W1, b1, W2, dinv, xws_h);
    k_gcn<<<G_GCN, 256, 0, stream>>>(xws_h, dinv, scol, off, cnt, b2, out);
}